// Round 9
// baseline (182.272 us; speedup 1.0000x reference)
//
#include <hip/hip_runtime.h>
#include <hip/hip_bf16.h>
#include <stdint.h>

// Problem constants: B=2, S=2048, E=1024, H=16, hd=64.
#define SS 2048
#define EE 1024
#define HH 16
#define HD 64

// 0.125 (1/sqrt(hd)) * log2(e): scores come out of QK^T already in exp2-domain.
#define QSCALE 0.1803368801111137f

typedef __attribute__((ext_vector_type(8))) short short8;
typedef __attribute__((ext_vector_type(4))) float f32x4;

__device__ __forceinline__ short f2bf(float f) {
  union { float f; uint32_t u; } x; x.f = f;
  uint32_t r = x.u + 0x7fffu + ((x.u >> 16) & 1u);
  return (short)(r >> 16);
}

__device__ __forceinline__ uint32_t pk_bf16(float a, float b) {
#if __has_builtin(__builtin_amdgcn_cvt_pk_bf16_f32)
  typedef __attribute__((ext_vector_type(2))) __bf16 bf16x2_t;
  union { bf16x2_t v; uint32_t u; } x;
  x.v = __builtin_amdgcn_cvt_pk_bf16_f32(a, b);
  return x.u;
#else
  return (uint32_t)(uint16_t)f2bf(a) | ((uint32_t)(uint16_t)f2bf(b) << 16);
#endif
}

#if __has_builtin(__builtin_amdgcn_exp2f)
#define EXP2F __builtin_amdgcn_exp2f
#else
#define EXP2F exp2f
#endif

__device__ __forceinline__ void async_cp16(const void* g, void* l) {
  __builtin_amdgcn_global_load_lds((const __attribute__((address_space(1))) void*)g,
                                   (__attribute__((address_space(3))) void*)l, 16, 0, 0);
}

// ---------------- fp32 -> bf16 pre-convert (X, W_in, W_out) ----------------
// R22: grid-stride at 2048 blocks (G11) instead of 8192 one-shot blocks.
#define N4_X  1048576
#define N4_W1 786432
#define N4_W2 262144
#define N4_ALL (N4_X + N4_W1 + N4_W2)
__global__ __launch_bounds__(256) void cvt_all(
    const float* __restrict__ x, const float* __restrict__ w1,
    const float* __restrict__ w2,
    short* __restrict__ xb, short* __restrict__ w1b, short* __restrict__ w2b)
{
  for (int i = blockIdx.x * 256 + threadIdx.x; i < N4_ALL; i += 2048 * 256) {
    const float* src; short* dst; int off;
    if (i < N4_X)            { src = x;  dst = xb;  off = i; }
    else if (i < N4_X+N4_W1) { src = w1; dst = w1b; off = i - N4_X; }
    else                     { src = w2; dst = w2b; off = i - N4_X - N4_W1; }
    float4 v = *(const float4*)&src[(size_t)off * 4];
    uint2 pk;
    pk.x = pk_bf16(v.x, v.y);
    pk.y = pk_bf16(v.z, v.w);
    *(uint2*)&dst[(size_t)off * 4] = pk;
  }
}

// ====== QKV GEMM: BM=128 x BN=128, BK=32, dbuf async global->LDS (R18 exact) ======
// Orientation branch hoisted OUT of the K-loop (R2/R3 lesson: in-loop if(isV)
// de-pipelines, VALUBusy 17%->51%). Two duplicated branch-free main loops.
//   q/k loops use mfma(bfr, af): lane holds 4 consecutive d -> b64 restage.
//   v loop uses mfma(af, bfr):   lane holds 4 consecutive s -> b64 transpose
//   restage.
// NO manual vmcnt/sched_barrier pipelining: R19 tried and regressed 46->65 us.
// 8-phase/256^2 rewrite rejected on data: m248 (256^2, K=1024 regime) shows
// 2ph=655 vs 8ph=848 TF (1.29x) and our 256^2 grid packs 192/256 CUs (0.75x)
// -> net ~0 at this shape.
// V layout NOTE: within each 128-aligned s-block, shorts are stored kv-permuted:
//   stored position 32f+8t+4cc+r  holds  kv = 32f+16cc+4t+r.
// This makes the attention PV B-operand (P fragments) lane-local.
__global__ __launch_bounds__(256) void gemm_qkv(
    const short* __restrict__ A, const short* __restrict__ Bw,
    const float* __restrict__ bias,
    short* __restrict__ qw, short* __restrict__ kw, short* __restrict__ vw,
    int M, int N, int K)
{
  __shared__ short smem[17408];
  const int tid = threadIdx.x;
  const int lane = tid & 63;
  const int wv = tid >> 6;
  const int wm = (wv >> 1) * 64;
  const int wn = (wv & 1) * 64;
  const int t = lane >> 4;
  const int lr = lane & 15;
  const int bm = blockIdx.y * 128;
  const int bn = blockIdx.x * 128;

  f32x4 acc[4][4];
  #pragma unroll
  for (int i = 0; i < 4; ++i)
    #pragma unroll
    for (int j = 0; j < 4; ++j) acc[i][j] = (f32x4){0.f, 0.f, 0.f, 0.f};

  auto stage = [&](int buf, int k0) {
    short* sA = smem + buf * 8192;
    short* sB = smem + buf * 8192 + 4096;
    #pragma unroll
    for (int it = 0; it < 2; ++it) {
      int c = it * 256 + wv * 64 + lane;
      int row = c >> 2;
      int ch = (c & 3) * 8;
      async_cp16(&A[(size_t)(bm + row) * K + k0 + ch],
                 (char*)sA + (size_t)(it * 256 + wv * 64) * 16);
      async_cp16(&Bw[(size_t)(bn + row) * K + k0 + ch],
                 (char*)sB + (size_t)(it * 256 + wv * 64) * 16);
    }
  };

  const bool isV = (bn >= 2048);
  const bool isQ = (bn < 1024);
  const int nk = K >> 5;
  stage(0, 0);
  __syncthreads();

  if (isV) {
    // original orientation: lane holds 4 consecutive s (rows), col = d
    for (int k = 0; k < nk; ++k) {
      if (k + 1 < nk) stage((k + 1) & 1, (k + 1) << 5);
      const short* cA = smem + (k & 1) * 8192;
      const short* cB = smem + (k & 1) * 8192 + 4096;
      short8 af[4], bfr[4];
      #pragma unroll
      for (int i = 0; i < 4; ++i) af[i] = *(const short8*)&cA[(wm + i*16 + lr)*32 + t*8];
      #pragma unroll
      for (int j = 0; j < 4; ++j) bfr[j] = *(const short8*)&cB[(wn + j*16 + lr)*32 + t*8];
      #pragma unroll
      for (int i = 0; i < 4; ++i)
        #pragma unroll
        for (int j = 0; j < 4; ++j)
          acc[i][j] = __builtin_amdgcn_mfma_f32_16x16x32_bf16(af[i], bfr[j], acc[i][j], 0, 0, 0);
      __syncthreads();
    }
  } else {
    // transposed: lane holds 4 consecutive n/d (cols), row = s
    for (int k = 0; k < nk; ++k) {
      if (k + 1 < nk) stage((k + 1) & 1, (k + 1) << 5);
      const short* cA = smem + (k & 1) * 8192;
      const short* cB = smem + (k & 1) * 8192 + 4096;
      short8 af[4], bfr[4];
      #pragma unroll
      for (int i = 0; i < 4; ++i) af[i] = *(const short8*)&cA[(wm + i*16 + lr)*32 + t*8];
      #pragma unroll
      for (int j = 0; j < 4; ++j) bfr[j] = *(const short8*)&cB[(wn + j*16 + lr)*32 + t*8];
      #pragma unroll
      for (int i = 0; i < 4; ++i)
        #pragma unroll
        for (int j = 0; j < 4; ++j)
          acc[i][j] = __builtin_amdgcn_mfma_f32_16x16x32_bf16(bfr[j], af[i], acc[i][j], 0, 0, 0);
      __syncthreads();
    }
  }

  short* vx = smem;                      // [128][136] restage buffer
  int b_ = bm >> 11;
  int s0 = bm & 2047;
  if (isV) {
    // v: transpose restage [d-col][s-row]; lane's 4 consecutive s pack to b64
    #pragma unroll
    for (int i = 0; i < 4; ++i) {
      int row0 = wm + i*16 + t*4;        // s-base, multiple of 4
      #pragma unroll
      for (int j = 0; j < 4; ++j) {
        int cl = wn + j*16 + lr;         // d-col within block
        float bv = bias[bn + cl];
        uint2 pw;
        pw.x = pk_bf16(acc[i][j][0] + bv, acc[i][j][1] + bv);
        pw.y = pk_bf16(acc[i][j][2] + bv, acc[i][j][3] + bv);
        *(uint2*)&vx[cl*136 + row0] = pw;
      }
    }
    __syncthreads();
    int h0 = (bn - 2048) >> 6;
    #pragma unroll
    for (int it = 0; it < 8; ++it) {
      int cc = it * 256 + tid;
      int cl = cc >> 4;
      int ck = cc & 15;                  // 16B chunk = stored positions 8ck..8ck+7
      int h = h0 + (cl >> 6);
      int d = cl & 63;
      int f = ck >> 2, tt = ck & 3;
      const short* src = &vx[cl*136 + 32*f + 4*tt];
      uint2 lo = *(const uint2*)src;          // kv = 32f+4t+0..3      (cc=0)
      uint2 hi = *(const uint2*)(src + 16);   // kv = 32f+16+4t+0..3   (cc=1)
      uint4 val; val.x = lo.x; val.y = lo.y; val.z = hi.x; val.w = hi.y;
      *(uint4*)&vw[((size_t)(b_*HH + h)*HD + d)*SS + s0 + ck*8] = val;
    }
  } else {
    // q/k: transposed frag -> restage [s-row][d-col]; 4 consecutive d pack to b64
    #pragma unroll
    for (int j = 0; j < 4; ++j) {
      int col0 = wn + j*16 + t*4;        // d-col base within block, multiple of 4
      float4 bv4 = *(const float4*)&bias[bn + col0];
      #pragma unroll
      for (int i = 0; i < 4; ++i) {
        int row = wm + i*16 + lr;        // s-row within block
        float v0 = acc[i][j][0] + bv4.x;
        float v1 = acc[i][j][1] + bv4.y;
        float v2 = acc[i][j][2] + bv4.z;
        float v3 = acc[i][j][3] + bv4.w;
        if (isQ) { v0 *= QSCALE; v1 *= QSCALE; v2 *= QSCALE; v3 *= QSCALE; }
        uint2 pw;
        pw.x = pk_bf16(v0, v1);
        pw.y = pk_bf16(v2, v3);
        *(uint2*)&vx[row*136 + col0] = pw;
      }
    }
    __syncthreads();
    short* dst = isQ ? qw : kw;
    int h0 = (bn & 1023) >> 6;
    #pragma unroll
    for (int it = 0; it < 8; ++it) {
      int cc = it * 256 + tid;
      int row = cc >> 4;               // 0..127 (s offset)
      int ck = cc & 15;                // 16B chunk along cols
      int h = h0 + (ck >> 3);
      int d0 = (ck & 7) * 8;
      *(uint4*)&dst[((size_t)(b_*HH + h)*SS + s0 + row)*HD + d0] =
          *(const uint4*)&vx[row*136 + ck*8];
    }
  }
}

// ====== Out-proj GEMM: BM=64 x BN=128 (R4/R14 tile, best-total config), fp32 out ======
__global__ __launch_bounds__(256) void gemm_out(
    const short* __restrict__ A, const short* __restrict__ Bw,
    const float* __restrict__ bias,
    float* __restrict__ C,
    int M, int N, int K)
{
  __shared__ short smem[12288];
  const int tid = threadIdx.x;
  const int lane = tid & 63;
  const int wv = tid >> 6;
  const int wm = (wv >> 1) * 32;
  const int wn = (wv & 1) * 64;
  const int t = lane >> 4;
  const int lr = lane & 15;
  const int bm = blockIdx.y * 64;
  const int bn = blockIdx.x * 128;

  f32x4 acc[2][4];
  #pragma unroll
  for (int i = 0; i < 2; ++i)
    #pragma unroll
    for (int j = 0; j < 4; ++j) acc[i][j] = (f32x4){0.f, 0.f, 0.f, 0.f};

  auto stage = [&](int buf, int k0) {
    short* sA = smem + buf * 6144;
    short* sB = smem + buf * 6144 + 2048;
    {
      int c = wv * 64 + lane;            // A 64x32 = 256 chunks
      int row = c >> 2;
      int ch = (c & 3) * 8;
      async_cp16(&A[(size_t)(bm + row) * K + k0 + ch],
                 (char*)sA + (size_t)(wv * 64) * 16);
    }
    #pragma unroll
    for (int it = 0; it < 2; ++it) {     // B 128x32 = 512 chunks
      int c = it * 256 + wv * 64 + lane;
      int row = c >> 2;
      int ch = (c & 3) * 8;
      async_cp16(&Bw[(size_t)(bn + row) * K + k0 + ch],
                 (char*)sB + (size_t)(it * 256 + wv * 64) * 16);
    }
  };

  const int nk = K >> 5;
  stage(0, 0);
  __syncthreads();

  for (int k = 0; k < nk; ++k) {
    if (k + 1 < nk) stage((k + 1) & 1, (k + 1) << 5);
    const short* cA = smem + (k & 1) * 6144;
    const short* cB = smem + (k & 1) * 6144 + 2048;
    short8 af[2], bfr[4];
    #pragma unroll
    for (int i = 0; i < 2; ++i) af[i] = *(const short8*)&cA[(wm + i*16 + lr)*32 + t*8];
    #pragma unroll
    for (int j = 0; j < 4; ++j) bfr[j] = *(const short8*)&cB[(wn + j*16 + lr)*32 + t*8];
    #pragma unroll
    for (int i = 0; i < 2; ++i)
      #pragma unroll
      for (int j = 0; j < 4; ++j)
        acc[i][j] = __builtin_amdgcn_mfma_f32_16x16x32_bf16(af[i], bfr[j], acc[i][j], 0, 0, 0);
    __syncthreads();
  }

  #pragma unroll
  for (int i = 0; i < 2; ++i) {
    int row0 = bm + wm + i*16 + t*4;
    #pragma unroll
    for (int j = 0; j < 4; ++j) {
      int col = bn + wn + j*16 + lr;
      float bv = bias[col];
      #pragma unroll
      for (int r = 0; r < 4; ++r)
        C[(size_t)(row0 + r) * N + col] = acc[i][j][r] + bv;
    }
  }
}

// ------------- fallback GEMM (fp32 staging convert), for ws < 48 MB -------------
template<int MODE, typename TA>
__global__ __launch_bounds__(256) void gemm_bt(
    const TA* __restrict__ A, const float* __restrict__ Bw,
    const float* __restrict__ bias,
    float* __restrict__ C,
    short* __restrict__ qw, short* __restrict__ kw, short* __restrict__ vw,
    int M, int N, int K)
{
  __shared__ short sA[128*32];
  __shared__ short sB[128*32];
  const int tid = threadIdx.x;
  const int lane = tid & 63;
  const int wv = tid >> 6;
  const int wm = (wv >> 1) * 64;
  const int wn = (wv & 1) * 64;
  const int t = lane >> 4;
  const int lr = lane & 15;
  const int bm = blockIdx.y * 128;
  const int bn = blockIdx.x * 128;

  f32x4 acc[4][4];
  #pragma unroll
  for (int i = 0; i < 4; ++i)
    #pragma unroll
    for (int j = 0; j < 4; ++j) acc[i][j] = (f32x4){0.f, 0.f, 0.f, 0.f};

  for (int k0 = 0; k0 < K; k0 += 32) {
    __syncthreads();
    if constexpr (sizeof(TA) == 4) {
      #pragma unroll
      for (int it = 0; it < 4; ++it) {
        int c = it * 256 + tid;
        int row = c >> 3, ch = (c & 7) * 4;
        float4 va = *(const float4*)&A[(size_t)(bm + row)*K + k0 + ch];
        uint2 pk; pk.x = pk_bf16(va.x, va.y); pk.y = pk_bf16(va.z, va.w);
        *(uint2*)&sA[row*32 + ch] = pk;
      }
    } else {
      #pragma unroll
      for (int it = 0; it < 2; ++it) {
        int c = it * 256 + tid;
        int row = c >> 2, ch = (c & 3) * 8;
        *(uint4*)&sA[row*32 + ch] = *(const uint4*)&A[(size_t)(bm + row)*K + k0 + ch];
      }
    }
    #pragma unroll
    for (int it = 0; it < 4; ++it) {
      int c = it * 256 + tid;
      int row = c >> 3, ch = (c & 7) * 4;
      float4 vb = *(const float4*)&Bw[(size_t)(bn + row)*K + k0 + ch];
      uint2 pk; pk.x = pk_bf16(vb.x, vb.y); pk.y = pk_bf16(vb.z, vb.w);
      *(uint2*)&sB[row*32 + ch] = pk;
    }
    __syncthreads();
    short8 af[4], bfr[4];
    #pragma unroll
    for (int i = 0; i < 4; ++i) af[i] = *(const short8*)&sA[(wm + i*16 + lr)*32 + t*8];
    #pragma unroll
    for (int j = 0; j < 4; ++j) bfr[j] = *(const short8*)&sB[(wn + j*16 + lr)*32 + t*8];
    #pragma unroll
    for (int i = 0; i < 4; ++i)
      #pragma unroll
      for (int j = 0; j < 4; ++j)
        acc[i][j] = __builtin_amdgcn_mfma_f32_16x16x32_bf16(af[i], bfr[j], acc[i][j], 0, 0, 0);
  }

  #pragma unroll
  for (int i = 0; i < 4; ++i) {
    int row0 = bm + wm + i*16 + t*4;
    #pragma unroll
    for (int j = 0; j < 4; ++j) {
      int col = bn + wn + j*16 + lr;
      float bv = bias[col];
      #pragma unroll
      for (int r = 0; r < 4; ++r) {
        float v = acc[i][j][r] + bv;
        int rr = row0 + r;
        if (MODE == 0) {
          C[(size_t)rr * N + col] = v;
        } else {
          int which = col >> 10;
          int e = col & 1023;
          int h = e >> 6, d = e & 63;
          int b_ = rr >> 11, s = rr & 2047;
          if (which == 0)
            qw[((size_t)(b_*HH + h)*SS + s)*HD + d] = f2bf(v * QSCALE);
          else if (which == 1)
            kw[((size_t)(b_*HH + h)*SS + s)*HD + d] = f2bf(v);
          else {
            // kv-permuted V layout (must match gemm_qkv / attn PV):
            // k bits [6:5]=f,[4]=cc,[3:2]=t,[1:0]=r  ->  pos = 32f+8t+4cc+r
            int k7 = s & 127;
            int sp = (k7 & 0x60) | ((k7 & 0x0C) << 1) | ((k7 & 0x10) >> 2) | (k7 & 3);
            vw[((size_t)(b_*HH + h)*HD + d)*SS + (s & ~127) + sp] = f2bf(v);
          }
        }
      }
    }
  }
}

// ---------------- causal flash attention: NO-RESCALE softmax ----------------
// R22: diagonal (masked) tile split OUT of the main loop. Wave w only needs
// score chunks c <= w there (kv rows 16c..16c+15 vs its q rows 16w..16w+15);
// guards are wave-uniform `if (c > w) continue` on fully-unrolled loops
// (static register indexing preserved -- rule #20). Mask simplifies to
// 4t+r > lr at c==w. sc[] pre-zeroed and exp2 guarded, so skipped chunks
// contribute 0 to rs and PV. No barrier after the diagonal tile.
// Main loop iterations are mask-free and identical to R4's proven body.
// 8 waves x 16 q-rows, Br=128, Bc=128; grid 512 (2 blocks/CU), qt pairing
// balances long+short tiles (iters per CU-pair = 17 constant).
// Vt is stored kv-permuted (see gemm_qkv), so MFMA k-slot j=4cc+r of
// lane-group t carries kv=32f+16cc+4t+r in BOTH the V (A) and P (B) operands;
// pf is built lane-locally from sc via cvt_pk only.
__global__ __launch_bounds__(512) void attn_kernel(
    const short* __restrict__ Q, const short* __restrict__ K,
    const short* __restrict__ Vt, short* __restrict__ O)
{
  __shared__ short sK[2][128*64];   // swizzled: row kv, chunk cc stored at (cc^(kv&7))
  __shared__ short sV[2][64*128];   // swizzled: row d, chunk cc stored at (cc^(d&15))
  const int tid = threadIdx.x;
  const int lane = tid & 63;
  const int w = tid >> 6;
  const int t = lane >> 4;
  const int lr = lane & 15;
  const int blk = blockIdx.x;
  const int qt = (blk < 256) ? (blk >> 5) : (15 - ((blk - 256) >> 5));
  const int bh = blk & 31;
  const int b = bh >> 4, h = bh & 15;
  const short* Qb = Q  + (size_t)bh * SS * HD;
  const short* Kb = K  + (size_t)bh * SS * HD;
  const short* Vb = Vt + (size_t)bh * HD * SS;
  const int qrow0 = qt * 128 + w * 16;

  auto stage = [&](int buf, int kb) {
    #pragma unroll
    for (int it2 = 0; it2 < 2; ++it2) {
      int s = it2 * 512 + tid;
      int krow = s >> 3;
      int kcc = (s & 7) ^ (krow & 7);
      async_cp16(&Kb[(size_t)(kb + krow) * HD + kcc * 8],
                 (char*)sK[buf] + (size_t)(it2 * 512 + w * 64) * 16);
      int d = s >> 4;
      int vcc = (s & 15) ^ (d & 15);
      async_cp16(&Vb[(size_t)d * SS + kb + vcc * 8],
                 (char*)sV[buf] + (size_t)(it2 * 512 + w * 64) * 16);
    }
  };

  short8 qf[2];
  #pragma unroll
  for (int st = 0; st < 2; ++st)
    qf[st] = *(const short8*)&Qb[(size_t)(qrow0 + lr) * HD + st*32 + t*8];

  f32x4 o[4];                      // o^T: o[jd][r] = O^T[d = jd*16 + 4t + r][q = lr]
  #pragma unroll
  for (int jd = 0; jd < 4; ++jd) o[jd] = (f32x4){0.f, 0.f, 0.f, 0.f};
  float l = 0.f;                   // per-lane: this lane's q-row = qrow0 + lr

  const int niter = qt + 1;
  stage(0, 0);
  __syncthreads();
  int cur = 0;

  // ---- full (unmasked) iterations: it = 0 .. niter-2 ----
  #pragma unroll 1
  for (int it = 0; it < niter - 1; ++it) {
    const int kb = it * 128;
    stage(cur ^ 1, kb + 128);
    const short* sKc = sK[cur];
    const short* sVc = sV[cur];

    // S^T = K * Q^T : lane owns q-col lr; sc[c][r] = S^T[kv = 16c+4t+r][q = lr]
    f32x4 sc[8];
    #pragma unroll
    for (int c = 0; c < 8; ++c) sc[c] = (f32x4){0.f,0.f,0.f,0.f};
    __builtin_amdgcn_s_setprio(1);
    #pragma unroll
    for (int c = 0; c < 8; ++c) {
      int krow = c*16 + lr;
      #pragma unroll
      for (int st = 0; st < 2; ++st) {
        int slot = krow*8 + ((st*4 + t) ^ (lr & 7));
        short8 kf = *(const short8*)&sKc[slot*8];
        sc[c] = __builtin_amdgcn_mfma_f32_16x16x32_bf16(kf, qf[st], sc[c], 0, 0, 0);
      }
    }
    __builtin_amdgcn_s_setprio(0);

    // no-rescale softmax: exponentiate + accumulate row sum (4 indep chains)
    float rs0 = 0.f, rs1 = 0.f, rs2 = 0.f, rs3 = 0.f;
    #pragma unroll
    for (int c = 0; c < 8; ++c) {
      sc[c][0] = EXP2F(sc[c][0]);
      sc[c][1] = EXP2F(sc[c][1]);
      sc[c][2] = EXP2F(sc[c][2]);
      sc[c][3] = EXP2F(sc[c][3]);
      rs0 += sc[c][0];
      rs1 += sc[c][1];
      rs2 += sc[c][2];
      rs3 += sc[c][3];
    }
    float rs = (rs0 + rs1) + (rs2 + rs3);
    rs += __shfl_xor(rs, 16);
    rs += __shfl_xor(rs, 32);
    l += rs;

    // PV: pf built in-register (lane-local). For k-group f (kv 32f..32f+31):
    //   pf[j=4cc+r] = P[32f+16cc+4t+r][lr] = sc[2f+cc][r]
    //   vf[j=4cc+r] = V^T[d][32f+16cc+4t+r]
    __builtin_amdgcn_s_setprio(1);
    #pragma unroll
    for (int f = 0; f < 4; ++f) {
      union { uint32_t u[4]; short8 s8; } up;
      up.u[0] = pk_bf16(sc[2*f  ][0], sc[2*f  ][1]);
      up.u[1] = pk_bf16(sc[2*f  ][2], sc[2*f  ][3]);
      up.u[2] = pk_bf16(sc[2*f+1][0], sc[2*f+1][1]);
      up.u[3] = pk_bf16(sc[2*f+1][2], sc[2*f+1][3]);
      short8 pf = up.s8;
      #pragma unroll
      for (int jd = 0; jd < 4; ++jd) {
        int d = jd*16 + lr;
        int vslot = d*16 + ((f*4 + t) ^ lr);
        short8 vf = *(const short8*)&sVc[vslot*8];
        o[jd] = __builtin_amdgcn_mfma_f32_16x16x32_bf16(vf, pf, o[jd], 0, 0, 0);
      }
    }
    __builtin_amdgcn_s_setprio(0);

    __syncthreads();
    cur ^= 1;
  }

  // ---- diagonal (masked) tile: kb = qt*128, buffer cur ----
  {
    const short* sKc = sK[cur];
    const short* sVc = sV[cur];

    f32x4 sc[8];
    #pragma unroll
    for (int c = 0; c < 8; ++c) sc[c] = (f32x4){0.f,0.f,0.f,0.f};
    __builtin_amdgcn_s_setprio(1);
    #pragma unroll
    for (int c = 0; c < 8; ++c) {
      if (c > w) continue;             // wave-uniform: kv rows above diagonal
      int krow = c*16 + lr;
      #pragma unroll
      for (int st = 0; st < 2; ++st) {
        int slot = krow*8 + ((st*4 + t) ^ (lr & 7));
        short8 kf = *(const short8*)&sKc[slot*8];
        sc[c] = __builtin_amdgcn_mfma_f32_16x16x32_bf16(kf, qf[st], sc[c], 0, 0, 0);
      }
    }
    __builtin_amdgcn_s_setprio(0);

    // mask only c == w: pos-qrow0 = 4t+r vs lr
    #pragma unroll
    for (int c = 0; c < 8; ++c) {
      if (c != w) continue;
      #pragma unroll
      for (int r = 0; r < 4; ++r)
        if (4*t + r > lr) sc[c][r] = -1e30f;
    }

    float rs0 = 0.f, rs1 = 0.f, rs2 = 0.f, rs3 = 0.f;
    #pragma unroll
    for (int c = 0; c < 8; ++c) {
      if (c > w) continue;             // untouched chunks stay exactly 0
      sc[c][0] = EXP2F(sc[c][0]);
      sc[c][1] = EXP2F(sc[c][1]);
      sc[c][2] = EXP2F(sc[c][2]);
      sc[c][3] = EXP2F(sc[c][3]);
      rs0 += sc[c][0];
      rs1 += sc[c][1];
      rs2 += sc[c][2];
      rs3 += sc[c][3];
    }
    float rs = (rs0 + rs1) + (rs2 + rs3);
    rs += __shfl_xor(rs, 16);
    rs += __shfl_xor(rs, 32);
    l += rs;

    __builtin_amdgcn_s_setprio(1);
    #pragma unroll
    for (int f = 0; f < 4; ++f) {
      if (f > (w >> 1)) continue;      // both chunks of this k-group masked
      union { uint32_t u[4]; short8 s8; } up;
      up.u[0] = pk_bf16(sc[2*f  ][0], sc[2*f  ][1]);
      up.u[1] = pk_bf16(sc[2*f  ][2], sc[2*f  ][3]);
      up.u[2] = pk_bf16(sc[2*f+1][0], sc[2*f+1][1]);
      up.u[3] = pk_bf16(sc[2*f+1][2], sc[2*f+1][3]);
      short8 pf = up.s8;
      #pragma unroll
      for (int jd = 0; jd < 4; ++jd) {
        int d = jd*16 + lr;
        int vslot = d*16 + ((f*4 + t) ^ lr);
        short8 vf = *(const short8*)&sVc[vslot*8];
        o[jd] = __builtin_amdgcn_mfma_f32_16x16x32_bf16(vf, pf, o[jd], 0, 0, 0);
      }
    }
    __builtin_amdgcn_s_setprio(0);
  }

  // writeout: lane owns q = qrow0 + lr; d = jd*16 + 4t + r (4 consecutive per jd)
  float linv = 1.0f / l;
  size_t rowoff = ((size_t)(b * SS + qrow0 + lr)) * EE + h * HD;
  #pragma unroll
  for (int jd = 0; jd < 4; ++jd) {
    uint2 pw;
    pw.x = pk_bf16(o[jd][0] * linv, o[jd][1] * linv);
    pw.y = pk_bf16(o[jd][2] * linv, o[jd][3] * linv);
    *(uint2*)&O[rowoff + jd*16 + t*4] = pw;
  }
}

extern "C" void kernel_launch(void* const* d_in, const int* in_sizes, int n_in,
                              void* d_out, int out_size, void* d_ws, size_t ws_size,
                              hipStream_t stream) {
  const float* X     = (const float*)d_in[0];
  const float* W_in  = (const float*)d_in[1];
  const float* b_in  = (const float*)d_in[2];
  const float* W_out = (const float*)d_in[3];
  const float* b_out = (const float*)d_in[4];
  float* out = (float*)d_out;

  char* ws = (char*)d_ws;
  const size_t MB = 1024 * 1024;
  const int M = 2 * SS;  // 4096

  if (ws_size >= 48 * MB) {
    short* Xb   = (short*)(ws);
    short* Wb1  = (short*)(ws + 8  * MB);
    short* Wb2  = (short*)(ws + 14 * MB);
    short* q_ws = (short*)(ws + 16 * MB);
    short* k_ws = (short*)(ws + 24 * MB);
    short* v_ws = (short*)(ws + 32 * MB);
    short* attn = (short*)(ws + 40 * MB);

    cvt_all<<<2048, 256, 0, stream>>>(X, W_in, W_out, Xb, Wb1, Wb2);
    gemm_qkv<<<dim3(24, 32), 256, 0, stream>>>(
        Xb, Wb1, b_in, q_ws, k_ws, v_ws, M, 3 * EE, EE);
    attn_kernel<<<dim3(512), 512, 0, stream>>>(q_ws, k_ws, v_ws, attn);
    gemm_out<<<dim3(8, 64), 256, 0, stream>>>(
        attn, Wb2, b_out, out, M, EE, EE);
  } else {
    short* q_ws = (short*)(ws);
    short* k_ws = (short*)(ws + 8  * MB);
    short* v_ws = (short*)(ws + 16 * MB);
    short* attn = (short*)(ws + 24 * MB);

    gemm_bt<1, float><<<dim3(24, 32), 256, 0, stream>>>(
        X, W_in, b_in, nullptr, q_ws, k_ws, v_ws, M, 3 * EE, EE);
    attn_kernel<<<dim3(512), 512, 0, stream>>>(q_ws, k_ws, v_ws, attn);
    gemm_bt<0, short><<<dim3(8, 32), 256, 0, stream>>>(
        attn, W_out, b_out, out, nullptr, nullptr, nullptr, M, EE, EE);
  }
}

// Round 10
// 176.324 us; speedup vs baseline: 1.0337x; 1.0337x over previous
//
#include <hip/hip_runtime.h>
#include <hip/hip_bf16.h>
#include <stdint.h>

// Problem constants: B=2, S=2048, E=1024, H=16, hd=64.
#define SS 2048
#define EE 1024
#define HH 16
#define HD 64

// 0.125 (1/sqrt(hd)) * log2(e): scores come out of QK^T already in exp2-domain.
#define QSCALE 0.1803368801111137f

typedef __attribute__((ext_vector_type(8))) short short8;
typedef __attribute__((ext_vector_type(4))) float f32x4;

__device__ __forceinline__ short f2bf(float f) {
  union { float f; uint32_t u; } x; x.f = f;
  uint32_t r = x.u + 0x7fffu + ((x.u >> 16) & 1u);
  return (short)(r >> 16);
}

__device__ __forceinline__ uint32_t pk_bf16(float a, float b) {
#if __has_builtin(__builtin_amdgcn_cvt_pk_bf16_f32)
  typedef __attribute__((ext_vector_type(2))) __bf16 bf16x2_t;
  union { bf16x2_t v; uint32_t u; } x;
  x.v = __builtin_amdgcn_cvt_pk_bf16_f32(a, b);
  return x.u;
#else
  return (uint32_t)(uint16_t)f2bf(a) | ((uint32_t)(uint16_t)f2bf(b) << 16);
#endif
}

#if __has_builtin(__builtin_amdgcn_exp2f)
#define EXP2F __builtin_amdgcn_exp2f
#else
#define EXP2F exp2f
#endif

__device__ __forceinline__ void async_cp16(const void* g, void* l) {
  __builtin_amdgcn_global_load_lds((const __attribute__((address_space(1))) void*)g,
                                   (__attribute__((address_space(3))) void*)l, 16, 0, 0);
}

// ---------------- fp32 -> bf16 pre-convert (X, W_in, W_out) ----------------
// Grid-stride at 2048 blocks (G11). Measured ~6 TB/s -> at HBM roofline.
#define N4_X  1048576
#define N4_W1 786432
#define N4_W2 262144
#define N4_ALL (N4_X + N4_W1 + N4_W2)
__global__ __launch_bounds__(256) void cvt_all(
    const float* __restrict__ x, const float* __restrict__ w1,
    const float* __restrict__ w2,
    short* __restrict__ xb, short* __restrict__ w1b, short* __restrict__ w2b)
{
  for (int i = blockIdx.x * 256 + threadIdx.x; i < N4_ALL; i += 2048 * 256) {
    const float* src; short* dst; int off;
    if (i < N4_X)            { src = x;  dst = xb;  off = i; }
    else if (i < N4_X+N4_W1) { src = w1; dst = w1b; off = i - N4_X; }
    else                     { src = w2; dst = w2b; off = i - N4_X - N4_W1; }
    float4 v = *(const float4*)&src[(size_t)off * 4];
    uint2 pk;
    pk.x = pk_bf16(v.x, v.y);
    pk.y = pk_bf16(v.z, v.w);
    *(uint2*)&dst[(size_t)off * 4] = pk;
  }
}

// ====== QKV GEMM: BM=128 x BN=128, BK=32, dbuf async global->LDS (R18 loop) ======
// Orientation branch hoisted OUT of the K-loop (R2/R3 lesson: in-loop if(isV)
// de-pipelines, VALUBusy 17%->51%). Two duplicated branch-free main loops.
//   q/k loops use mfma(bfr, af): lane holds 4 consecutive d -> b64 restage.
//   v loop uses mfma(af, bfr):   lane holds 4 consecutive s -> b64 transpose
//   restage.
// R23: bias loads hoisted ABOVE the K-loop (epilogue-time global loads were a
// post-barrier latency bubble; pre-loop loads hide under the 32 K-iters).
// NO manual vmcnt/sched_barrier pipelining: R19 tried and regressed 46->65 us.
// 8-phase/256^2 rejected on data: m248 K=1024 regime = 1.29x * 0.75 packing.
// V layout NOTE: within each 128-aligned s-block, shorts are stored kv-permuted:
//   stored position 32f+8t+4cc+r  holds  kv = 32f+16cc+4t+r.
// This makes the attention PV B-operand (P fragments) lane-local.
__global__ __launch_bounds__(256) void gemm_qkv(
    const short* __restrict__ A, const short* __restrict__ Bw,
    const float* __restrict__ bias,
    short* __restrict__ qw, short* __restrict__ kw, short* __restrict__ vw,
    int M, int N, int K)
{
  __shared__ short smem[17408];
  const int tid = threadIdx.x;
  const int lane = tid & 63;
  const int wv = tid >> 6;
  const int wm = (wv >> 1) * 64;
  const int wn = (wv & 1) * 64;
  const int t = lane >> 4;
  const int lr = lane & 15;
  const int bm = blockIdx.y * 128;
  const int bn = blockIdx.x * 128;

  f32x4 acc[4][4];
  #pragma unroll
  for (int i = 0; i < 4; ++i)
    #pragma unroll
    for (int j = 0; j < 4; ++j) acc[i][j] = (f32x4){0.f, 0.f, 0.f, 0.f};

  auto stage = [&](int buf, int k0) {
    short* sA = smem + buf * 8192;
    short* sB = smem + buf * 8192 + 4096;
    #pragma unroll
    for (int it = 0; it < 2; ++it) {
      int c = it * 256 + wv * 64 + lane;
      int row = c >> 2;
      int ch = (c & 3) * 8;
      async_cp16(&A[(size_t)(bm + row) * K + k0 + ch],
                 (char*)sA + (size_t)(it * 256 + wv * 64) * 16);
      async_cp16(&Bw[(size_t)(bn + row) * K + k0 + ch],
                 (char*)sB + (size_t)(it * 256 + wv * 64) * 16);
    }
  };

  const bool isV = (bn >= 2048);
  const bool isQ = (bn < 1024);
  const int nk = K >> 5;
  stage(0, 0);
  __syncthreads();

  if (isV) {
    // R23: prefetch V-epilogue bias (per d-col) before the K-loop
    float bvv[4];
    #pragma unroll
    for (int j = 0; j < 4; ++j) bvv[j] = bias[bn + wn + j*16 + lr];

    // original orientation: lane holds 4 consecutive s (rows), col = d
    for (int k = 0; k < nk; ++k) {
      if (k + 1 < nk) stage((k + 1) & 1, (k + 1) << 5);
      const short* cA = smem + (k & 1) * 8192;
      const short* cB = smem + (k & 1) * 8192 + 4096;
      short8 af[4], bfr[4];
      #pragma unroll
      for (int i = 0; i < 4; ++i) af[i] = *(const short8*)&cA[(wm + i*16 + lr)*32 + t*8];
      #pragma unroll
      for (int j = 0; j < 4; ++j) bfr[j] = *(const short8*)&cB[(wn + j*16 + lr)*32 + t*8];
      #pragma unroll
      for (int i = 0; i < 4; ++i)
        #pragma unroll
        for (int j = 0; j < 4; ++j)
          acc[i][j] = __builtin_amdgcn_mfma_f32_16x16x32_bf16(af[i], bfr[j], acc[i][j], 0, 0, 0);
      __syncthreads();
    }

    short* vx = smem;                    // [128][136] restage buffer
    int b_ = bm >> 11;
    int s0 = bm & 2047;
    // v: transpose restage [d-col][s-row]; lane's 4 consecutive s pack to b64
    #pragma unroll
    for (int i = 0; i < 4; ++i) {
      int row0 = wm + i*16 + t*4;        // s-base, multiple of 4
      #pragma unroll
      for (int j = 0; j < 4; ++j) {
        int cl = wn + j*16 + lr;         // d-col within block
        float bv = bvv[j];
        uint2 pw;
        pw.x = pk_bf16(acc[i][j][0] + bv, acc[i][j][1] + bv);
        pw.y = pk_bf16(acc[i][j][2] + bv, acc[i][j][3] + bv);
        *(uint2*)&vx[cl*136 + row0] = pw;
      }
    }
    __syncthreads();
    int h0 = (bn - 2048) >> 6;
    #pragma unroll
    for (int it = 0; it < 8; ++it) {
      int cc = it * 256 + tid;
      int cl = cc >> 4;
      int ck = cc & 15;                  // 16B chunk = stored positions 8ck..8ck+7
      int h = h0 + (cl >> 6);
      int d = cl & 63;
      int f = ck >> 2, tt = ck & 3;
      const short* src = &vx[cl*136 + 32*f + 4*tt];
      uint2 lo = *(const uint2*)src;          // kv = 32f+4t+0..3      (cc=0)
      uint2 hi = *(const uint2*)(src + 16);   // kv = 32f+16+4t+0..3   (cc=1)
      uint4 val; val.x = lo.x; val.y = lo.y; val.z = hi.x; val.w = hi.y;
      *(uint4*)&vw[((size_t)(b_*HH + h)*HD + d)*SS + s0 + ck*8] = val;
    }
  } else {
    // R23: prefetch q/k-epilogue bias (4 consecutive d per lane) before K-loop
    float4 bq[4];
    #pragma unroll
    for (int j = 0; j < 4; ++j) bq[j] = *(const float4*)&bias[bn + wn + j*16 + t*4];

    // transposed: lane holds 4 consecutive n/d (cols), row = s
    for (int k = 0; k < nk; ++k) {
      if (k + 1 < nk) stage((k + 1) & 1, (k + 1) << 5);
      const short* cA = smem + (k & 1) * 8192;
      const short* cB = smem + (k & 1) * 8192 + 4096;
      short8 af[4], bfr[4];
      #pragma unroll
      for (int i = 0; i < 4; ++i) af[i] = *(const short8*)&cA[(wm + i*16 + lr)*32 + t*8];
      #pragma unroll
      for (int j = 0; j < 4; ++j) bfr[j] = *(const short8*)&cB[(wn + j*16 + lr)*32 + t*8];
      #pragma unroll
      for (int i = 0; i < 4; ++i)
        #pragma unroll
        for (int j = 0; j < 4; ++j)
          acc[i][j] = __builtin_amdgcn_mfma_f32_16x16x32_bf16(bfr[j], af[i], acc[i][j], 0, 0, 0);
      __syncthreads();
    }

    short* vx = smem;                    // [128][136] restage buffer
    int b_ = bm >> 11;
    int s0 = bm & 2047;
    // q/k: transposed frag -> restage [s-row][d-col]; 4 consecutive d pack to b64
    #pragma unroll
    for (int j = 0; j < 4; ++j) {
      int col0 = wn + j*16 + t*4;        // d-col base within block, multiple of 4
      float4 bv4 = bq[j];
      #pragma unroll
      for (int i = 0; i < 4; ++i) {
        int row = wm + i*16 + lr;        // s-row within block
        float v0 = acc[i][j][0] + bv4.x;
        float v1 = acc[i][j][1] + bv4.y;
        float v2 = acc[i][j][2] + bv4.z;
        float v3 = acc[i][j][3] + bv4.w;
        if (isQ) { v0 *= QSCALE; v1 *= QSCALE; v2 *= QSCALE; v3 *= QSCALE; }
        uint2 pw;
        pw.x = pk_bf16(v0, v1);
        pw.y = pk_bf16(v2, v3);
        *(uint2*)&vx[row*136 + col0] = pw;
      }
    }
    __syncthreads();
    short* dst = isQ ? qw : kw;
    int h0 = (bn & 1023) >> 6;
    #pragma unroll
    for (int it = 0; it < 8; ++it) {
      int cc = it * 256 + tid;
      int row = cc >> 4;               // 0..127 (s offset)
      int ck = cc & 15;                // 16B chunk along cols
      int h = h0 + (ck >> 3);
      int d0 = (ck & 7) * 8;
      *(uint4*)&dst[((size_t)(b_*HH + h)*SS + s0 + row)*HD + d0] =
          *(const uint4*)&vx[row*136 + ck*8];
    }
  }
}

// ====== Out-proj GEMM: BM=64 x BN=128 (R4/R14 tile, best-total config), fp32 out ======
// R23: bias prefetched above the K-loop (same rationale as gemm_qkv).
__global__ __launch_bounds__(256) void gemm_out(
    const short* __restrict__ A, const short* __restrict__ Bw,
    const float* __restrict__ bias,
    float* __restrict__ C,
    int M, int N, int K)
{
  __shared__ short smem[12288];
  const int tid = threadIdx.x;
  const int lane = tid & 63;
  const int wv = tid >> 6;
  const int wm = (wv >> 1) * 32;
  const int wn = (wv & 1) * 64;
  const int t = lane >> 4;
  const int lr = lane & 15;
  const int bm = blockIdx.y * 64;
  const int bn = blockIdx.x * 128;

  f32x4 acc[2][4];
  #pragma unroll
  for (int i = 0; i < 2; ++i)
    #pragma unroll
    for (int j = 0; j < 4; ++j) acc[i][j] = (f32x4){0.f, 0.f, 0.f, 0.f};

  float bvo[4];
  #pragma unroll
  for (int j = 0; j < 4; ++j) bvo[j] = bias[bn + wn + j*16 + lr];

  auto stage = [&](int buf, int k0) {
    short* sA = smem + buf * 6144;
    short* sB = smem + buf * 6144 + 2048;
    {
      int c = wv * 64 + lane;            // A 64x32 = 256 chunks
      int row = c >> 2;
      int ch = (c & 3) * 8;
      async_cp16(&A[(size_t)(bm + row) * K + k0 + ch],
                 (char*)sA + (size_t)(wv * 64) * 16);
    }
    #pragma unroll
    for (int it = 0; it < 2; ++it) {     // B 128x32 = 512 chunks
      int c = it * 256 + wv * 64 + lane;
      int row = c >> 2;
      int ch = (c & 3) * 8;
      async_cp16(&Bw[(size_t)(bn + row) * K + k0 + ch],
                 (char*)sB + (size_t)(it * 256 + wv * 64) * 16);
    }
  };

  const int nk = K >> 5;
  stage(0, 0);
  __syncthreads();

  for (int k = 0; k < nk; ++k) {
    if (k + 1 < nk) stage((k + 1) & 1, (k + 1) << 5);
    const short* cA = smem + (k & 1) * 6144;
    const short* cB = smem + (k & 1) * 6144 + 2048;
    short8 af[2], bfr[4];
    #pragma unroll
    for (int i = 0; i < 2; ++i) af[i] = *(const short8*)&cA[(wm + i*16 + lr)*32 + t*8];
    #pragma unroll
    for (int j = 0; j < 4; ++j) bfr[j] = *(const short8*)&cB[(wn + j*16 + lr)*32 + t*8];
    #pragma unroll
    for (int i = 0; i < 2; ++i)
      #pragma unroll
      for (int j = 0; j < 4; ++j)
        acc[i][j] = __builtin_amdgcn_mfma_f32_16x16x32_bf16(af[i], bfr[j], acc[i][j], 0, 0, 0);
    __syncthreads();
  }

  #pragma unroll
  for (int i = 0; i < 2; ++i) {
    int row0 = bm + wm + i*16 + t*4;
    #pragma unroll
    for (int j = 0; j < 4; ++j) {
      int col = bn + wn + j*16 + lr;
      float bv = bvo[j];
      #pragma unroll
      for (int r = 0; r < 4; ++r)
        C[(size_t)(row0 + r) * N + col] = acc[i][j][r] + bv;
    }
  }
}

// ------------- fallback GEMM (fp32 staging convert), for ws < 48 MB -------------
template<int MODE, typename TA>
__global__ __launch_bounds__(256) void gemm_bt(
    const TA* __restrict__ A, const float* __restrict__ Bw,
    const float* __restrict__ bias,
    float* __restrict__ C,
    short* __restrict__ qw, short* __restrict__ kw, short* __restrict__ vw,
    int M, int N, int K)
{
  __shared__ short sA[128*32];
  __shared__ short sB[128*32];
  const int tid = threadIdx.x;
  const int lane = tid & 63;
  const int wv = tid >> 6;
  const int wm = (wv >> 1) * 64;
  const int wn = (wv & 1) * 64;
  const int t = lane >> 4;
  const int lr = lane & 15;
  const int bm = blockIdx.y * 128;
  const int bn = blockIdx.x * 128;

  f32x4 acc[4][4];
  #pragma unroll
  for (int i = 0; i < 4; ++i)
    #pragma unroll
    for (int j = 0; j < 4; ++j) acc[i][j] = (f32x4){0.f, 0.f, 0.f, 0.f};

  for (int k0 = 0; k0 < K; k0 += 32) {
    __syncthreads();
    if constexpr (sizeof(TA) == 4) {
      #pragma unroll
      for (int it = 0; it < 4; ++it) {
        int c = it * 256 + tid;
        int row = c >> 3, ch = (c & 7) * 4;
        float4 va = *(const float4*)&A[(size_t)(bm + row)*K + k0 + ch];
        uint2 pk; pk.x = pk_bf16(va.x, va.y); pk.y = pk_bf16(va.z, va.w);
        *(uint2*)&sA[row*32 + ch] = pk;
      }
    } else {
      #pragma unroll
      for (int it = 0; it < 2; ++it) {
        int c = it * 256 + tid;
        int row = c >> 2, ch = (c & 3) * 8;
        *(uint4*)&sA[row*32 + ch] = *(const uint4*)&A[(size_t)(bm + row)*K + k0 + ch];
      }
    }
    #pragma unroll
    for (int it = 0; it < 4; ++it) {
      int c = it * 256 + tid;
      int row = c >> 3, ch = (c & 7) * 4;
      float4 vb = *(const float4*)&Bw[(size_t)(bn + row)*K + k0 + ch];
      uint2 pk; pk.x = pk_bf16(vb.x, vb.y); pk.y = pk_bf16(vb.z, vb.w);
      *(uint2*)&sB[row*32 + ch] = pk;
    }
    __syncthreads();
    short8 af[4], bfr[4];
    #pragma unroll
    for (int i = 0; i < 4; ++i) af[i] = *(const short8*)&sA[(wm + i*16 + lr)*32 + t*8];
    #pragma unroll
    for (int j = 0; j < 4; ++j) bfr[j] = *(const short8*)&sB[(wn + j*16 + lr)*32 + t*8];
    #pragma unroll
    for (int i = 0; i < 4; ++i)
      #pragma unroll
      for (int j = 0; j < 4; ++j)
        acc[i][j] = __builtin_amdgcn_mfma_f32_16x16x32_bf16(af[i], bfr[j], acc[i][j], 0, 0, 0);
  }

  #pragma unroll
  for (int i = 0; i < 4; ++i) {
    int row0 = bm + wm + i*16 + t*4;
    #pragma unroll
    for (int j = 0; j < 4; ++j) {
      int col = bn + wn + j*16 + lr;
      float bv = bias[col];
      #pragma unroll
      for (int r = 0; r < 4; ++r) {
        float v = acc[i][j][r] + bv;
        int rr = row0 + r;
        if (MODE == 0) {
          C[(size_t)rr * N + col] = v;
        } else {
          int which = col >> 10;
          int e = col & 1023;
          int h = e >> 6, d = e & 63;
          int b_ = rr >> 11, s = rr & 2047;
          if (which == 0)
            qw[((size_t)(b_*HH + h)*SS + s)*HD + d] = f2bf(v * QSCALE);
          else if (which == 1)
            kw[((size_t)(b_*HH + h)*SS + s)*HD + d] = f2bf(v);
          else {
            // kv-permuted V layout (must match gemm_qkv / attn PV):
            // k bits [6:5]=f,[4]=cc,[3:2]=t,[1:0]=r  ->  pos = 32f+8t+4cc+r
            int k7 = s & 127;
            int sp = (k7 & 0x60) | ((k7 & 0x0C) << 1) | ((k7 & 0x10) >> 2) | (k7 & 3);
            vw[((size_t)(b_*HH + h)*HD + d)*SS + (s & ~127) + sp] = f2bf(v);
          }
        }
      }
    }
  }
}

// ---------------- causal flash attention: NO-RESCALE softmax ----------------
// Diagonal (masked) tile split OUT of the main loop (R22). Wave w only needs
// score chunks c <= w there; guards are wave-uniform `if (c > w) continue` on
// fully-unrolled loops (static register indexing preserved -- rule #20).
// Mask simplifies to 4t+r > lr at c==w. sc[] pre-zeroed and exp2 guarded, so
// skipped chunks contribute 0 to rs and PV. No barrier after the diagonal.
// Main loop iterations are mask-free. 8 waves x 16 q-rows, Br=128, Bc=128;
// grid 512 (2 blocks/CU = 16 waves/CU -- the structural optimum: fewer q-rows
// per wave wastes MFMA M-dim, more q-rows halves occupancy and lost in R20).
// Vt is stored kv-permuted (see gemm_qkv), so MFMA k-slot j=4cc+r of
// lane-group t carries kv=32f+16cc+4t+r in BOTH the V (A) and P (B) operands;
// pf is built lane-locally from sc via cvt_pk only.
__global__ __launch_bounds__(512) void attn_kernel(
    const short* __restrict__ Q, const short* __restrict__ K,
    const short* __restrict__ Vt, short* __restrict__ O)
{
  __shared__ short sK[2][128*64];   // swizzled: row kv, chunk cc stored at (cc^(kv&7))
  __shared__ short sV[2][64*128];   // swizzled: row d, chunk cc stored at (cc^(d&15))
  const int tid = threadIdx.x;
  const int lane = tid & 63;
  const int w = tid >> 6;
  const int t = lane >> 4;
  const int lr = lane & 15;
  const int blk = blockIdx.x;
  const int qt = (blk < 256) ? (blk >> 5) : (15 - ((blk - 256) >> 5));
  const int bh = blk & 31;
  const int b = bh >> 4, h = bh & 15;
  const short* Qb = Q  + (size_t)bh * SS * HD;
  const short* Kb = K  + (size_t)bh * SS * HD;
  const short* Vb = Vt + (size_t)bh * HD * SS;
  const int qrow0 = qt * 128 + w * 16;

  auto stage = [&](int buf, int kb) {
    #pragma unroll
    for (int it2 = 0; it2 < 2; ++it2) {
      int s = it2 * 512 + tid;
      int krow = s >> 3;
      int kcc = (s & 7) ^ (krow & 7);
      async_cp16(&Kb[(size_t)(kb + krow) * HD + kcc * 8],
                 (char*)sK[buf] + (size_t)(it2 * 512 + w * 64) * 16);
      int d = s >> 4;
      int vcc = (s & 15) ^ (d & 15);
      async_cp16(&Vb[(size_t)d * SS + kb + vcc * 8],
                 (char*)sV[buf] + (size_t)(it2 * 512 + w * 64) * 16);
    }
  };

  short8 qf[2];
  #pragma unroll
  for (int st = 0; st < 2; ++st)
    qf[st] = *(const short8*)&Qb[(size_t)(qrow0 + lr) * HD + st*32 + t*8];

  f32x4 o[4];                      // o^T: o[jd][r] = O^T[d = jd*16 + 4t + r][q = lr]
  #pragma unroll
  for (int jd = 0; jd < 4; ++jd) o[jd] = (f32x4){0.f, 0.f, 0.f, 0.f};
  float l = 0.f;                   // per-lane: this lane's q-row = qrow0 + lr

  const int niter = qt + 1;
  stage(0, 0);
  __syncthreads();
  int cur = 0;

  // ---- full (unmasked) iterations: it = 0 .. niter-2 ----
  #pragma unroll 1
  for (int it = 0; it < niter - 1; ++it) {
    const int kb = it * 128;
    stage(cur ^ 1, kb + 128);
    const short* sKc = sK[cur];
    const short* sVc = sV[cur];

    // S^T = K * Q^T : lane owns q-col lr; sc[c][r] = S^T[kv = 16c+4t+r][q = lr]
    f32x4 sc[8];
    #pragma unroll
    for (int c = 0; c < 8; ++c) sc[c] = (f32x4){0.f,0.f,0.f,0.f};
    __builtin_amdgcn_s_setprio(1);
    #pragma unroll
    for (int c = 0; c < 8; ++c) {
      int krow = c*16 + lr;
      #pragma unroll
      for (int st = 0; st < 2; ++st) {
        int slot = krow*8 + ((st*4 + t) ^ (lr & 7));
        short8 kf = *(const short8*)&sKc[slot*8];
        sc[c] = __builtin_amdgcn_mfma_f32_16x16x32_bf16(kf, qf[st], sc[c], 0, 0, 0);
      }
    }
    __builtin_amdgcn_s_setprio(0);

    // no-rescale softmax: exponentiate + accumulate row sum (4 indep chains)
    float rs0 = 0.f, rs1 = 0.f, rs2 = 0.f, rs3 = 0.f;
    #pragma unroll
    for (int c = 0; c < 8; ++c) {
      sc[c][0] = EXP2F(sc[c][0]);
      sc[c][1] = EXP2F(sc[c][1]);
      sc[c][2] = EXP2F(sc[c][2]);
      sc[c][3] = EXP2F(sc[c][3]);
      rs0 += sc[c][0];
      rs1 += sc[c][1];
      rs2 += sc[c][2];
      rs3 += sc[c][3];
    }
    float rs = (rs0 + rs1) + (rs2 + rs3);
    rs += __shfl_xor(rs, 16);
    rs += __shfl_xor(rs, 32);
    l += rs;

    // PV: pf built in-register (lane-local). For k-group f (kv 32f..32f+31):
    //   pf[j=4cc+r] = P[32f+16cc+4t+r][lr] = sc[2f+cc][r]
    //   vf[j=4cc+r] = V^T[d][32f+16cc+4t+r]
    __builtin_amdgcn_s_setprio(1);
    #pragma unroll
    for (int f = 0; f < 4; ++f) {
      union { uint32_t u[4]; short8 s8; } up;
      up.u[0] = pk_bf16(sc[2*f  ][0], sc[2*f  ][1]);
      up.u[1] = pk_bf16(sc[2*f  ][2], sc[2*f  ][3]);
      up.u[2] = pk_bf16(sc[2*f+1][0], sc[2*f+1][1]);
      up.u[3] = pk_bf16(sc[2*f+1][2], sc[2*f+1][3]);
      short8 pf = up.s8;
      #pragma unroll
      for (int jd = 0; jd < 4; ++jd) {
        int d = jd*16 + lr;
        int vslot = d*16 + ((f*4 + t) ^ lr);
        short8 vf = *(const short8*)&sVc[vslot*8];
        o[jd] = __builtin_amdgcn_mfma_f32_16x16x32_bf16(vf, pf, o[jd], 0, 0, 0);
      }
    }
    __builtin_amdgcn_s_setprio(0);

    __syncthreads();
    cur ^= 1;
  }

  // ---- diagonal (masked) tile: kb = qt*128, buffer cur ----
  {
    const short* sKc = sK[cur];
    const short* sVc = sV[cur];

    f32x4 sc[8];
    #pragma unroll
    for (int c = 0; c < 8; ++c) sc[c] = (f32x4){0.f,0.f,0.f,0.f};
    __builtin_amdgcn_s_setprio(1);
    #pragma unroll
    for (int c = 0; c < 8; ++c) {
      if (c > w) continue;             // wave-uniform: kv rows above diagonal
      int krow = c*16 + lr;
      #pragma unroll
      for (int st = 0; st < 2; ++st) {
        int slot = krow*8 + ((st*4 + t) ^ (lr & 7));
        short8 kf = *(const short8*)&sKc[slot*8];
        sc[c] = __builtin_amdgcn_mfma_f32_16x16x32_bf16(kf, qf[st], sc[c], 0, 0, 0);
      }
    }
    __builtin_amdgcn_s_setprio(0);

    // mask only c == w: pos-qrow0 = 4t+r vs lr
    #pragma unroll
    for (int c = 0; c < 8; ++c) {
      if (c != w) continue;
      #pragma unroll
      for (int r = 0; r < 4; ++r)
        if (4*t + r > lr) sc[c][r] = -1e30f;
    }

    float rs0 = 0.f, rs1 = 0.f, rs2 = 0.f, rs3 = 0.f;
    #pragma unroll
    for (int c = 0; c < 8; ++c) {
      if (c > w) continue;             // untouched chunks stay exactly 0
      sc[c][0] = EXP2F(sc[c][0]);
      sc[c][1] = EXP2F(sc[c][1]);
      sc[c][2] = EXP2F(sc[c][2]);
      sc[c][3] = EXP2F(sc[c][3]);
      rs0 += sc[c][0];
      rs1 += sc[c][1];
      rs2 += sc[c][2];
      rs3 += sc[c][3];
    }
    float rs = (rs0 + rs1) + (rs2 + rs3);
    rs += __shfl_xor(rs, 16);
    rs += __shfl_xor(rs, 32);
    l += rs;

    __builtin_amdgcn_s_setprio(1);
    #pragma unroll
    for (int f = 0; f < 4; ++f) {
      if (f > (w >> 1)) continue;      // both chunks of this k-group masked
      union { uint32_t u[4]; short8 s8; } up;
      up.u[0] = pk_bf16(sc[2*f  ][0], sc[2*f  ][1]);
      up.u[1] = pk_bf16(sc[2*f  ][2], sc[2*f  ][3]);
      up.u[2] = pk_bf16(sc[2*f+1][0], sc[2*f+1][1]);
      up.u[3] = pk_bf16(sc[2*f+1][2], sc[2*f+1][3]);
      short8 pf = up.s8;
      #pragma unroll
      for (int jd = 0; jd < 4; ++jd) {
        int d = jd*16 + lr;
        int vslot = d*16 + ((f*4 + t) ^ lr);
        short8 vf = *(const short8*)&sVc[vslot*8];
        o[jd] = __builtin_amdgcn_mfma_f32_16x16x32_bf16(vf, pf, o[jd], 0, 0, 0);
      }
    }
    __builtin_amdgcn_s_setprio(0);
  }

  // writeout: lane owns q = qrow0 + lr; d = jd*16 + 4t + r (4 consecutive per jd)
  float linv = 1.0f / l;
  size_t rowoff = ((size_t)(b * SS + qrow0 + lr)) * EE + h * HD;
  #pragma unroll
  for (int jd = 0; jd < 4; ++jd) {
    uint2 pw;
    pw.x = pk_bf16(o[jd][0] * linv, o[jd][1] * linv);
    pw.y = pk_bf16(o[jd][2] * linv, o[jd][3] * linv);
    *(uint2*)&O[rowoff + jd*16 + t*4] = pw;
  }
}

extern "C" void kernel_launch(void* const* d_in, const int* in_sizes, int n_in,
                              void* d_out, int out_size, void* d_ws, size_t ws_size,
                              hipStream_t stream) {
  const float* X     = (const float*)d_in[0];
  const float* W_in  = (const float*)d_in[1];
  const float* b_in  = (const float*)d_in[2];
  const float* W_out = (const float*)d_in[3];
  const float* b_out = (const float*)d_in[4];
  float* out = (float*)d_out;

  char* ws = (char*)d_ws;
  const size_t MB = 1024 * 1024;
  const int M = 2 * SS;  // 4096

  if (ws_size >= 48 * MB) {
    short* Xb   = (short*)(ws);
    short* Wb1  = (short*)(ws + 8  * MB);
    short* Wb2  = (short*)(ws + 14 * MB);
    short* q_ws = (short*)(ws + 16 * MB);
    short* k_ws = (short*)(ws + 24 * MB);
    short* v_ws = (short*)(ws + 32 * MB);
    short* attn = (short*)(ws + 40 * MB);

    cvt_all<<<2048, 256, 0, stream>>>(X, W_in, W_out, Xb, Wb1, Wb2);
    gemm_qkv<<<dim3(24, 32), 256, 0, stream>>>(
        Xb, Wb1, b_in, q_ws, k_ws, v_ws, M, 3 * EE, EE);
    attn_kernel<<<dim3(512), 512, 0, stream>>>(q_ws, k_ws, v_ws, attn);
    gemm_out<<<dim3(8, 64), 256, 0, stream>>>(
        attn, Wb2, b_out, out, M, EE, EE);
  } else {
    short* q_ws = (short*)(ws);
    short* k_ws = (short*)(ws + 8  * MB);
    short* v_ws = (short*)(ws + 16 * MB);
    short* attn = (short*)(ws + 24 * MB);

    gemm_bt<1, float><<<dim3(24, 32), 256, 0, stream>>>(
        X, W_in, b_in, nullptr, q_ws, k_ws, v_ws, M, 3 * EE, EE);
    attn_kernel<<<dim3(512), 512, 0, stream>>>(q_ws, k_ws, v_ws, attn);
    gemm_bt<0, short><<<dim3(8, 32), 256, 0, stream>>>(
        attn, W_out, b_out, out, nullptr, nullptr, nullptr, M, EE, EE);
  }
}